// Round 1
// baseline (8986.124 us; speedup 1.0000x reference)
//
#include <hip/hip_runtime.h>

// Problem dims
// B=2048, T=TM1=128, N=64, H=128
// inputs: 0 X(2048,128,64) 1 W_attn1(128,384) 2 b_attn1(128) 3 w_attn2(128)
//         4 b_attn2(1)[unused: softmax shift-invariant] 5 W_ih(512,64) 6 W_hh(512,128)
//         7 b_ih(512) 8 b_hh(512)
// output: (2048,128,128) f32
// d_ws layout: Wt (128x128 f32 transposed W1_x) @ 0, pre_x (2048x64x128 f32) @ +16384 floats
// ws needed = (16384 + 16777216)*4 B ~= 64.1 MiB

#define LOG2E 1.44269504088896340736f

__device__ __forceinline__ float rcpf(float x){ return __builtin_amdgcn_rcpf(x); }
__device__ __forceinline__ float fast_exp(float x){ return __builtin_exp2f(x * LOG2E); }
__device__ __forceinline__ float fast_tanh(float x){
  // tanh(x) = 1 - 2/(exp(2x)+1); saturates correctly for |x| large
  float e = __builtin_exp2f(x * (2.0f * LOG2E));
  return 1.0f - 2.0f * rcpf(e + 1.0f);
}
__device__ __forceinline__ float fast_sig(float x){
  float e = __builtin_exp2f(x * (-LOG2E));
  return rcpf(1.0f + e);
}
__device__ __forceinline__ void ld4(const float* p, float* d){
  float4 v = *(const float4*)p;
  d[0]=v.x; d[1]=v.y; d[2]=v.z; d[3]=v.w;
}

// ---------------- k0: transpose W1_x -> Wt[t][k] ----------------
__global__ __launch_bounds__(256) void k0_wt(const float* __restrict__ Wat,
                                             float* __restrict__ Wt){
  int idx = blockIdx.x*256 + threadIdx.x;   // 16384 total
  int t = idx >> 7, k = idx & 127;
  Wt[idx] = Wat[k*384 + 256 + t];
}

// ---------------- k1: pre_x[b][n][k] = sum_t X[b][t][n]*W1_x[k][t] + b1[k] ----
__global__ __launch_bounds__(256) void k1_prex(const float* __restrict__ X,
                                               const float* __restrict__ Wt,
                                               const float* __restrict__ b1,
                                               float* __restrict__ prex){
  __shared__ float Xs[128][64];             // X[b] staged, 32KB
  const int tid = threadIdx.x;
  const long b = blockIdx.x;
  {
    const float4* X4 = (const float4*)(X + b*8192);
    float4* Xs4 = (float4*)&Xs[0][0];
    #pragma unroll
    for (int i=0;i<8;i++) Xs4[tid + i*256] = X4[tid + i*256];
  }
  __syncthreads();
  const int nq = tid >> 4, kq = tid & 15;   // n-tile of 4, k-tile of 8
  float acc[4][8];
  #pragma unroll
  for (int n=0;n<4;n++)
    #pragma unroll
    for (int k=0;k<8;k++) acc[n][k]=0.f;
  #pragma unroll 4
  for (int t=0;t<128;t++){
    float wv[8], xv[4];
    ld4(Wt + t*128 + kq*8, wv); ld4(Wt + t*128 + kq*8 + 4, wv+4);
    ld4(&Xs[t][nq*4], xv);
    #pragma unroll
    for (int n=0;n<4;n++)
      #pragma unroll
      for (int k=0;k<8;k++) acc[n][k] = fmaf(xv[n], wv[k], acc[n][k]);
  }
  float bv[8]; ld4(b1 + kq*8, bv); ld4(b1 + kq*8 + 4, bv+4);
  #pragma unroll
  for (int n=0;n<4;n++){
    float* dst = prex + (b*64 + nq*4 + n)*128 + kq*8;
    *(float4*)(dst)   = make_float4(acc[n][0]+bv[0], acc[n][1]+bv[1],
                                    acc[n][2]+bv[2], acc[n][3]+bv[3]);
    *(float4*)(dst+4) = make_float4(acc[n][4]+bv[4], acc[n][5]+bv[5],
                                    acc[n][6]+bv[6], acc[n][7]+bv[7]);
  }
}

// ---------------- k2: persistent recurrent kernel ----------------
// 256 blocks x 1024 threads; block owns 8 batch elements for all 128 steps.
// All weights register-hoisted (unique slice per thread), activations via LDS,
// contraction partials reduced with shfl_xor butterflies over 16-lane groups.
__global__ __launch_bounds__(1024) void k2_lstm(const float* __restrict__ X,
                                                const float* __restrict__ Wat,
                                                const float* __restrict__ w2,
                                                const float* __restrict__ Wih,
                                                const float* __restrict__ Whh,
                                                const float* __restrict__ bih,
                                                const float* __restrict__ bhh,
                                                const float* __restrict__ prex,
                                                float* __restrict__ out){
  const int tid = threadIdx.x;
  const long b0 = (long)blockIdx.x * 8;

  __shared__ float hs[8][128];    // h state
  __shared__ float cs[8][128];    // c state
  __shared__ float aa[8][128];    // a_h + a_c
  __shared__ float ep[8][64][2];  // e partial sums (k-halves)
  __shared__ float xt[8][64];     // alpha * x_t
  __shared__ float w2s[128];
  __shared__ float blds[512];     // b_ih + b_hh

  // role indices: both P1 and P4 use (group = tid>>4, s = tid&15)
  const int grp = tid >> 4;       // P1: k-tile (2 k's); P4: gq-tile (2 gq's)
  const int sl  = tid & 15;       // contraction slice id
  const int p2_n = tid & 63, p2_b = (tid>>6)&7, p2_kh = tid>>9;
  const int out_b = tid>>7, out_j = tid&127;

  // ---- one-time register-hoisted weights
  float w1h[2][8], w1s[2][8];     // P1: rows k=grp*2+i, j-slice sl*8..+8 (h and c mats)
  #pragma unroll
  for (int i=0;i<2;i++){
    const float* r = Wat + (grp*2+i)*384 + sl*8;
    ld4(r,     &w1h[i][0]); ld4(r+4,   &w1h[i][4]);
    ld4(r+128, &w1s[i][0]); ld4(r+132, &w1s[i][4]);
  }
  float wih[2][4][4], whh[2][4][8]; // P4: rows g=grp*2+i+128q; n-slice sl*4..+4, j-slice sl*8..+8
  #pragma unroll
  for (int i=0;i<2;i++)
    #pragma unroll
    for (int q=0;q<4;q++){
      int g = grp*2 + i + 128*q;
      ld4(Wih + g*64 + sl*4, &wih[i][q][0]);
      const float* r = Whh + g*128 + sl*8;
      ld4(r, &whh[i][q][0]); ld4(r+4, &whh[i][q][4]);
    }

  // ---- init state + staged constants
  hs[tid>>7][tid&127] = 0.f;
  cs[tid>>7][tid&127] = 0.f;
  if (tid < 128) w2s[tid] = w2[tid];
  if (tid < 512) blds[tid] = bih[tid] + bhh[tid];
  __syncthreads();

  for (int t=0; t<128; ++t){
    // ---------- P1: aa[b][k] = h.W1h[k,:] + c.W1s[k,:]
    float p1a[8][2];
    #pragma unroll
    for (int bb=0;bb<8;bb++){
      float hv[8], cv[8];
      ld4(&hs[bb][sl*8], hv); ld4(&hs[bb][sl*8+4], hv+4);
      ld4(&cs[bb][sl*8], cv); ld4(&cs[bb][sl*8+4], cv+4);
      #pragma unroll
      for (int i=0;i<2;i++){
        float a = 0.f;
        #pragma unroll
        for (int j=0;j<8;j++){ a = fmaf(hv[j], w1h[i][j], a); a = fmaf(cv[j], w1s[i][j], a); }
        p1a[bb][i] = a;
      }
    }
    #pragma unroll
    for (int m=1;m<16;m<<=1)
      #pragma unroll
      for (int bb=0;bb<8;bb++)
        #pragma unroll
        for (int i=0;i<2;i++)
          p1a[bb][i] += __shfl_xor(p1a[bb][i], m, 64);
    { // lane sl writes (b=sl>>1, i=sl&1) — static-index select (no scratch)
      float v = 0.f;
      #pragma unroll
      for (int bb=0;bb<8;bb++)
        #pragma unroll
        for (int i=0;i<2;i++)
          if (sl == bb*2+i) v = p1a[bb][i];
      aa[sl>>1][grp*2 + (sl&1)] = v;
    }
    __syncthreads();

    // ---------- P2: ep = sum_k tanh(pre_x + aa) * w2   (k split in halves)
    {
      const float* px = prex + ((b0 + p2_b)*64 + p2_n)*128 + p2_kh*64;
      float ea0=0.f, ea1=0.f, ea2=0.f, ea3=0.f;
      #pragma unroll
      for (int i4=0;i4<16;i4++){
        float pv[4], av[4], wv[4];
        ld4(px + i4*4, pv);
        ld4(&aa[p2_b][p2_kh*64 + i4*4], av);
        ld4(&w2s[p2_kh*64 + i4*4], wv);
        ea0 = fmaf(fast_tanh(pv[0]+av[0]), wv[0], ea0);
        ea1 = fmaf(fast_tanh(pv[1]+av[1]), wv[1], ea1);
        ea2 = fmaf(fast_tanh(pv[2]+av[2]), wv[2], ea2);
        ea3 = fmaf(fast_tanh(pv[3]+av[3]), wv[3], ea3);
      }
      ep[p2_b][p2_n][p2_kh] = (ea0+ea1)+(ea2+ea3);
    }
    __syncthreads();

    // ---------- P3: softmax over n (64 lanes), xt = alpha * x_t
    if (tid < 512){
      int b = tid>>6, n = tid&63;
      float e = ep[b][n][0] + ep[b][n][1];
      float mx = e;
      #pragma unroll
      for (int m=32;m>=1;m>>=1) mx = fmaxf(mx, __shfl_xor(mx, m, 64));
      float p = fast_exp(e - mx);
      float sm = p;
      #pragma unroll
      for (int m=32;m>=1;m>>=1) sm += __shfl_xor(sm, m, 64);
      xt[b][n] = p * rcpf(sm) * X[(b0+b)*8192 + t*64 + n];
    }
    __syncthreads();

    // ---------- P4: gates = xt.Wih^T + h.Whh^T
    float p4a[8][2][4];
    #pragma unroll
    for (int bb=0;bb<8;bb++){
      float xv[4], hv[8];
      ld4(&xt[bb][sl*4], xv);
      ld4(&hs[bb][sl*8], hv); ld4(&hs[bb][sl*8+4], hv+4);
      #pragma unroll
      for (int i=0;i<2;i++)
        #pragma unroll
        for (int q=0;q<4;q++){
          float a = 0.f;
          #pragma unroll
          for (int n=0;n<4;n++) a = fmaf(xv[n], wih[i][q][n], a);
          #pragma unroll
          for (int j=0;j<8;j++) a = fmaf(hv[j], whh[i][q][j], a);
          p4a[bb][i][q] = a;
        }
    }
    #pragma unroll
    for (int m=1;m<16;m<<=1)
      #pragma unroll
      for (int bb=0;bb<8;bb++)
        #pragma unroll
        for (int i=0;i<2;i++)
          #pragma unroll
          for (int q=0;q<4;q++)
            p4a[bb][i][q] += __shfl_xor(p4a[bb][i][q], m, 64);
    __syncthreads();   // all hs/cs MAC-reads done before state writes

    // ---------- P4b: lane sl -> (b=sl>>1, gq=grp*2+(sl&1)) pointwise LSTM
    {
      float g4[4] = {0.f,0.f,0.f,0.f};
      #pragma unroll
      for (int bb=0;bb<8;bb++)
        #pragma unroll
        for (int i=0;i<2;i++){
          bool sel = (sl == bb*2+i);
          #pragma unroll
          for (int q=0;q<4;q++) g4[q] = sel ? p4a[bb][i][q] : g4[q];
        }
      int b = sl>>1, gq = grp*2 + (sl&1);
      float ig = fast_sig (g4[0] + blds[gq]);
      float fg = fast_sig (g4[1] + blds[gq+128]);
      float gg = fast_tanh(g4[2] + blds[gq+256]);
      float og = fast_sig (g4[3] + blds[gq+384]);
      float cn = fmaf(fg, cs[b][gq], ig*gg);
      float hn = og * fast_tanh(cn);
      cs[b][gq] = cn;
      hs[b][gq] = hn;
    }
    __syncthreads();

    // ---------- P5: coalesced output write
    out[(b0+out_b)*16384 + (long)t*128 + out_j] = hs[out_b][out_j];
  }
}

extern "C" void kernel_launch(void* const* d_in, const int* in_sizes, int n_in,
                              void* d_out, int out_size, void* d_ws, size_t ws_size,
                              hipStream_t stream) {
  const float* X   = (const float*)d_in[0];
  const float* Wat = (const float*)d_in[1];
  const float* b1  = (const float*)d_in[2];
  const float* w2  = (const float*)d_in[3];
  // d_in[4] = b_attn2: unused (softmax shift-invariance)
  const float* Wih = (const float*)d_in[5];
  const float* Whh = (const float*)d_in[6];
  const float* bih = (const float*)d_in[7];
  const float* bhh = (const float*)d_in[8];
  float* out  = (float*)d_out;
  float* Wt   = (float*)d_ws;          // 16384 floats
  float* prex = Wt + 16384;            // 2048*64*128 floats

  k0_wt  <<<64,   256, 0, stream>>>(Wat, Wt);
  k1_prex<<<2048, 256, 0, stream>>>(X, Wt, b1, prex);
  k2_lstm<<<256, 1024, 0, stream>>>(X, Wat, w2, Wih, Whh, bih, bhh, prex, out);
}